// Round 13
// baseline (102.309 us; speedup 1.0000x reference)
//
#include <hip/hip_runtime.h>
#include <hip/hip_bf16.h>

typedef __attribute__((ext_vector_type(8))) short bf16x8;
typedef __attribute__((ext_vector_type(4))) float f32x4;
typedef __attribute__((ext_vector_type(8))) unsigned short u16x8;
typedef __attribute__((ext_vector_type(4))) unsigned short u16x4;

__device__ __forceinline__ unsigned short f2bf_rtne(float f) {
    unsigned int u = __float_as_uint(f);
    u += 0x7FFFu + ((u >> 16) & 1u);
    return (unsigned short)(u >> 16);
}

__device__ __forceinline__ void gl2lds16(const void* g, void* l) {
    __builtin_amdgcn_global_load_lds((const __attribute__((address_space(1))) void*)g,
                                     (__attribute__((address_space(3))) void*)l, 16, 0, 0);
}

// ---------------- fused prep: job0/1 = f32->bf16 convert (x, x_hash); job2 = hash_weight ----------------
// blockIdx.y = job: interleaved across CUs (dispatch mixes jobs uniformly) — measured better
// than byte-proportional contiguous partitioning (hash job is VALU-bound, needs spreading).
// Hash VALU trim: fold 100*log2(e) into coefficients -> exp2f (drops the v_mul inside __expf);
// __fdividef for the softmax normalize. Mathematically equivalent (monotone rescale of logits).
#define NB 16
__global__ void prep_all(const float* __restrict__ x, const float* __restrict__ xh,
                         const float* __restrict__ w,
                         const float* __restrict__ a0, const float* __restrict__ a1,
                         const float* __restrict__ a2, const float* __restrict__ vals,
                         unsigned short* __restrict__ xb, unsigned short* __restrict__ xhb,
                         unsigned short* __restrict__ wbf, unsigned short* __restrict__ hwbf) {
    const int job = blockIdx.y;
    const int stride = gridDim.x * blockDim.x;
    int i = blockIdx.x * blockDim.x + threadIdx.x;
    if (job < 2) {
        const float* in = job ? xh : x;
        unsigned short* out = job ? xhb : xb;
        const int n8 = (4096 * 2048) / 8;
        for (; i < n8; i += stride) {
            const float4* p = (const float4*)in + (size_t)i * 2;
            float4 v0 = p[0];
            float4 v1 = p[1];
            u16x8 r;
            r[0] = f2bf_rtne(v0.x); r[1] = f2bf_rtne(v0.y); r[2] = f2bf_rtne(v0.z); r[3] = f2bf_rtne(v0.w);
            r[4] = f2bf_rtne(v1.x); r[5] = f2bf_rtne(v1.y); r[6] = f2bf_rtne(v1.z); r[7] = f2bf_rtne(v1.w);
            *((u16x8*)out + i) = r;
        }
    } else {
        const float TL2E = 100.0f * 1.4426950408889634f;  // T * log2(e)
        float A0[NB], A1[NB], A2[NB], V[NB];
#pragma unroll
        for (int b = 0; b < NB; ++b) {
            A0[b] = a0[b] * TL2E;
            A1[b] = a1[b] * TL2E;
            A2[b] = a2[b] * TL2E;
            V[b]  = vals[b];
        }
        const int n4 = (2048 * 2048) / 4;
        for (; i < n4; i += stride) {
            float4 wv = ((const float4*)w)[i];
            float win[4] = {wv.x, wv.y, wv.z, wv.w};
            u16x4 wr, hr;
#pragma unroll
            for (int c = 0; c < 4; ++c) {
                float xx = win[c];
                float x2 = xx * xx;
                float l[NB];
                float mx = -1e30f;
#pragma unroll
                for (int b = 0; b < NB; ++b) {
                    l[b] = fmaf(A1[b], xx, fmaf(A2[b], x2, A0[b]));   // logits * log2(e)
                    mx = fmaxf(mx, l[b]);
                }
                float s = 0.0f, acc = 0.0f;
#pragma unroll
                for (int b = 0; b < NB; ++b) {
                    float e = exp2f(l[b] - mx);                       // == exp(logit - max)
                    s += e;
                    acc = fmaf(e, V[b], acc);
                }
                wr[c] = f2bf_rtne(xx);
                hr[c] = f2bf_rtne(__fdividef(acc, s));
            }
            *((u16x4*)wbf + i)  = wr;
            *((u16x4*)hwbf + i) = hr;
        }
    }
}

// ---------------- 256x256-tile 8-phase bf16 GEMM: single-barrier phases (round-9, best) ----------------
// LOCKED: reproduced 65.2-66.4 us across r9/r11/r12. Round-7 read/stage/MFMA placement; ONE
// s_barrier between phases; end-barrier only after the vmcnt gates at P4/P8. Gate cover 4-6
// phases everywhere (audited). Conflicts 0; MfmaUtil ~43%. 1 block/CU is forced: LDS 128KB and
// acc 128 AGPR + 128 VGPR = 256 unified regs/wave x 8 waves = full CU register pool.
__global__ __launch_bounds__(512, 2) void gemm256(
    const unsigned short* __restrict__ Ax, const unsigned short* __restrict__ Ah,
    const unsigned short* __restrict__ Bw, const unsigned short* __restrict__ Bh,
    const float* __restrict__ bias,
    float* __restrict__ Cx, float* __restrict__ Chh) {
    const int K = 2048, N = 2048;

    __shared__ unsigned short lds[65536];  // A: [2][16384], B at +32768: [2][16384]

    const unsigned short* A  = blockIdx.z ? Ah : Ax;
    const unsigned short* Bm = blockIdx.z ? Bh : Bw;
    float* C = blockIdx.z ? Chh : Cx;

    const int tid  = threadIdx.x;
    const int lane = tid & 63;
    const int wid  = tid >> 6;
    const int wr = wid >> 2;          // 0..1 : wave row (128 rows)
    const int wc = wid & 3;           // 0..3 : wave col (64 cols)
    const int fr = lane & 15;
    const int fq = lane >> 4;         // 0..3
    const int brow = blockIdx.x;
    const int bcol = blockIdx.y;

    // staging source (pre-swizzled granule): thread t covers row (t>>3), physical granule (t&7)
    const int srow = tid >> 3;                              // 0..63
    const int sg8  = ((tid & 7) ^ (srow & 7)) * 8;          // logical k-offset (elements)
    const unsigned short* gA = A  + (size_t)(brow * 256 + srow) * K + sg8;
    const unsigned short* gB = Bm + (size_t)(bcol * 256 + srow) * K + sg8;
    const int wbase = wid * 512;                            // wave-uniform LDS base (ushorts)

    // ds_read swizzled granule offsets (round-2 pattern, measured 0-conflict)
    const int g0 = (fq ^ (fr & 7)) * 8;   // kk=0
    const int g1 = g0 ^ 32;               // kk=1

#define STAGE_A(buf, h, j) {                                                    \
    const unsigned short* _g = gA + (size_t)((h) * 128) * K + (j) * 64;         \
    gl2lds16(_g,                  lds + (buf) * 16384 + (h) * 8192 + wbase);    \
    gl2lds16(_g + (size_t)64 * K, lds + (buf) * 16384 + (h) * 8192 + 4096 + wbase); }
#define STAGE_B(buf, h, j) {                                                    \
    const unsigned short* _g = gB + (size_t)((h) * 128) * K + (j) * 64;         \
    gl2lds16(_g,                  lds + 32768 + (buf) * 16384 + (h) * 8192 + wbase); \
    gl2lds16(_g + (size_t)64 * K, lds + 32768 + (buf) * 16384 + (h) * 8192 + 4096 + wbase); }

#define RDA(dst, buf, mblk) {                                                   \
    const unsigned short* _p = lds + (buf) * 16384 + (wr * 128 + (mblk) * 16 + fr) * 64; \
    dst[0] = *(const bf16x8*)(_p + g0);                                         \
    dst[1] = *(const bf16x8*)(_p + g1); }
#define RDB(dst, buf, nblk) {                                                   \
    const unsigned short* _p = lds + 32768 + (buf) * 16384 + (wc * 64 + (nblk) * 16 + fr) * 64; \
    dst[0] = *(const bf16x8*)(_p + g0);                                         \
    dst[1] = *(const bf16x8*)(_p + g1); }
#define RD_BURST(buf) { RDB(bfr[0], buf, 0); RDB(bfr[1], buf, 1);               \
                        RDB(bfr[2], buf, 2); RDB(bfr[3], buf, 3); }

#define MM(mi, n, kk, AF) acc[mi][n] = __builtin_amdgcn_mfma_f32_16x16x32_bf16(AF[kk], bfr[n][kk], acc[mi][n], 0, 0, 0)

// phase: bar -> issue reads -> issue stage DMA -> MFMA (counted lgkm) -> [optional gate+bar]
#define PH(q, A0_, A1_, RDS, STG, TAILP) {                                      \
    __builtin_amdgcn_s_barrier();                                               \
    asm volatile("" ::: "memory");                                              \
    RDS;                                                                        \
    STG;                                                                        \
    __builtin_amdgcn_s_setprio(1);                                              \
    MM(2*(q),0,0,A0_); MM(2*(q),0,1,A0_); MM(2*(q)+1,0,0,A1_); MM(2*(q)+1,0,1,A1_); \
    MM(2*(q),1,0,A0_); MM(2*(q),1,1,A0_); MM(2*(q)+1,1,0,A1_); MM(2*(q)+1,1,1,A1_); \
    MM(2*(q),2,0,A0_); MM(2*(q),2,1,A0_); MM(2*(q)+1,2,0,A1_); MM(2*(q)+1,2,1,A1_); \
    MM(2*(q),3,0,A0_); MM(2*(q),3,1,A0_); MM(2*(q)+1,3,0,A1_); MM(2*(q)+1,3,1,A1_); \
    __builtin_amdgcn_s_setprio(0);                                              \
    TAILP;                                                                      \
    asm volatile("" ::: "memory"); }

#define GATE4 { asm volatile("s_waitcnt vmcnt(4)" ::: "memory");                \
                __builtin_amdgcn_s_barrier(); }
#define GATE0 { asm volatile("s_waitcnt vmcnt(0)" ::: "memory");                \
                __builtin_amdgcn_s_barrier(); }

    // prologue: A(0), B(0) -> buf0; B(1) -> buf1 (12 loads); vmcnt(4) leaves B(1) in flight
    STAGE_A(0, 0, 0); STAGE_A(0, 1, 0);
    STAGE_B(0, 0, 0); STAGE_B(0, 1, 0);
    STAGE_B(1, 0, 1); STAGE_B(1, 1, 1);
    asm volatile("s_waitcnt vmcnt(4)" ::: "memory");

    f32x4 acc[8][4] = {};
    bf16x8 bfr[4][2], aU0[2], aU1[2], aV0[2], aV1[2];

    // steady state: tiles 2t (buf0, P1-P4) and 2t+1 (buf1, P5-P8)
    // reads:  P1: burst(b0)+A01->U+A23->V   P2: A45->U   P3: A67->V   P4: -
    //         P5: burst(b1)+A01->U+A23->V   P6: A45->U   P7: A67->V   P8: -
    // stages: P1/P2: A(2t+1)->b1   P3/P4: B(2t+2)->b0 (P4 tail: gate vmcnt(4)+bar)
    //         P5/P6: A(2t+2)->b0   P7/P8: B(2t+3)->b1 (P8 tail: gate vmcnt(4)+bar)
#pragma unroll 1
    for (int t = 0; t < 15; ++t) {
        const int j1 = 2 * t + 1, j2 = 2 * t + 2, j3 = 2 * t + 3;
        PH(0, aU0, aU1, { RD_BURST(0); RDA(aU0,0,0); RDA(aU1,0,1); RDA(aV0,0,2); RDA(aV1,0,3); },
           STAGE_A(1, 0, j1), );
        PH(1, aV0, aV1, { RDA(aU0,0,4); RDA(aU1,0,5); }, STAGE_A(1, 1, j1), );
        PH(2, aU0, aU1, { RDA(aV0,0,6); RDA(aV1,0,7); }, STAGE_B(0, 0, j2), );
        PH(3, aV0, aV1, , STAGE_B(0, 1, j2), GATE4);
        PH(0, aU0, aU1, { RD_BURST(1); RDA(aU0,1,0); RDA(aU1,1,1); RDA(aV0,1,2); RDA(aV1,1,3); },
           STAGE_A(0, 0, j2), );
        PH(1, aV0, aV1, { RDA(aU0,1,4); RDA(aU1,1,5); }, STAGE_A(0, 1, j2), );
        PH(2, aU0, aU1, { RDA(aV0,1,6); RDA(aV1,1,7); }, STAGE_B(1, 0, j3), );
        PH(3, aV0, aV1, , STAGE_B(1, 1, j3), GATE4);
    }
    // tail: tiles 30 (buf0), 31 (buf1); A(31)->buf1 staged here, B(31) staged at t=14
    PH(0, aU0, aU1, { RD_BURST(0); RDA(aU0,0,0); RDA(aU1,0,1); RDA(aV0,0,2); RDA(aV1,0,3); },
       STAGE_A(1, 0, 31), );
    PH(1, aV0, aV1, { RDA(aU0,0,4); RDA(aU1,0,5); }, STAGE_A(1, 1, 31), );
    PH(2, aU0, aU1, { RDA(aV0,0,6); RDA(aV1,0,7); }, , );
    PH(3, aV0, aV1, , , GATE0);
    PH(0, aU0, aU1, { RD_BURST(1); RDA(aU0,1,0); RDA(aU1,1,1); RDA(aV0,1,2); RDA(aV1,1,3); }, , );
    PH(1, aV0, aV1, { RDA(aU0,1,4); RDA(aU1,1,5); }, , );
    PH(2, aU0, aU1, { RDA(aV0,1,6); RDA(aV1,1,7); }, , );
    PH(3, aV0, aV1, , , );

    // epilogue: C[row][col] = acc + bias; row = m*16 + fq*4 + r, col = n*16 + fr (verified mapping)
#pragma unroll
    for (int n = 0; n < 4; ++n) {
        const int col = bcol * 256 + wc * 64 + n * 16 + fr;
        const float bv = bias[col];
#pragma unroll
        for (int m = 0; m < 8; ++m) {
            const int row0 = brow * 256 + wr * 128 + m * 16 + fq * 4;
#pragma unroll
            for (int r = 0; r < 4; ++r)
                C[(size_t)(row0 + r) * N + col] = acc[m][n][r] + bv;
        }
    }
#undef STAGE_A
#undef STAGE_B
#undef RDA
#undef RDB
#undef RD_BURST
#undef MM
#undef PH
#undef GATE4
#undef GATE0
}

extern "C" void kernel_launch(void* const* d_in, const int* in_sizes, int n_in,
                              void* d_out, int out_size, void* d_ws, size_t ws_size,
                              hipStream_t stream) {
    const float* x    = (const float*)d_in[0];
    const float* xh   = (const float*)d_in[1];
    const float* w    = (const float*)d_in[2];
    const float* bias = (const float*)d_in[3];
    const float* a0   = (const float*)d_in[4];
    const float* a1   = (const float*)d_in[5];
    const float* a2   = (const float*)d_in[6];
    const float* vals = (const float*)d_in[7];

    float* out  = (float*)d_out;
    float* outh = out + (size_t)4096 * 2048;

    char* ws = (char*)d_ws;
    unsigned short* xb  = (unsigned short*)(ws);                              // 16 MB
    unsigned short* xhb = (unsigned short*)(ws + (size_t)16 * 1024 * 1024);   // 16 MB
    unsigned short* wb  = (unsigned short*)(ws + (size_t)32 * 1024 * 1024);   //  8 MB
    unsigned short* hwb = (unsigned short*)(ws + (size_t)40 * 1024 * 1024);   //  8 MB

    prep_all<<<dim3(2048, 3), 256, 0, stream>>>(x, xh, w, a0, a1, a2, vals, xb, xhb, wb, hwb);

    dim3 grid(4096 / 256, 2048 / 256, 2);
    gemm256<<<grid, 512, 0, stream>>>(xb, xhb, wb, hwb, bias, out, outh);
}

// Round 14
// 100.657 us; speedup vs baseline: 1.0164x; 1.0164x over previous
//
#include <hip/hip_runtime.h>
#include <hip/hip_bf16.h>

typedef __attribute__((ext_vector_type(8))) short bf16x8;
typedef __attribute__((ext_vector_type(4))) float f32x4;
typedef __attribute__((ext_vector_type(8))) unsigned short u16x8;
typedef __attribute__((ext_vector_type(4))) unsigned short u16x4;

__device__ __forceinline__ unsigned short f2bf_rtne(float f) {
    unsigned int u = __float_as_uint(f);
    u += 0x7FFFu + ((u >> 16) & 1u);
    return (unsigned short)(u >> 16);
}

__device__ __forceinline__ void gl2lds16(const void* g, void* l) {
    __builtin_amdgcn_global_load_lds((const __attribute__((address_space(1))) void*)g,
                                     (__attribute__((address_space(3))) void*)l, 16, 0, 0);
}

// ---------------- fused prep: job0/1 = f32->bf16 convert (x, x_hash); job2 = hash_weight ----------------
// blockIdx.y = job: interleaved across CUs. Hash trim: fold T*log2(e) into coefficients, then
// RAW v_exp_f32 via __builtin_amdgcn_exp2f (NOT exp2f — that's the precise libm path, measured
// 4us slower in r13). Net vs r12 (__expf): -16 v_mul/element. __fdividef for the normalize.
#define NB 16
__global__ void prep_all(const float* __restrict__ x, const float* __restrict__ xh,
                         const float* __restrict__ w,
                         const float* __restrict__ a0, const float* __restrict__ a1,
                         const float* __restrict__ a2, const float* __restrict__ vals,
                         unsigned short* __restrict__ xb, unsigned short* __restrict__ xhb,
                         unsigned short* __restrict__ wbf, unsigned short* __restrict__ hwbf) {
    const int job = blockIdx.y;
    const int stride = gridDim.x * blockDim.x;
    int i = blockIdx.x * blockDim.x + threadIdx.x;
    if (job < 2) {
        const float* in = job ? xh : x;
        unsigned short* out = job ? xhb : xb;
        const int n8 = (4096 * 2048) / 8;
        for (; i < n8; i += stride) {
            const float4* p = (const float4*)in + (size_t)i * 2;
            float4 v0 = p[0];
            float4 v1 = p[1];
            u16x8 r;
            r[0] = f2bf_rtne(v0.x); r[1] = f2bf_rtne(v0.y); r[2] = f2bf_rtne(v0.z); r[3] = f2bf_rtne(v0.w);
            r[4] = f2bf_rtne(v1.x); r[5] = f2bf_rtne(v1.y); r[6] = f2bf_rtne(v1.z); r[7] = f2bf_rtne(v1.w);
            *((u16x8*)out + i) = r;
        }
    } else {
        const float TL2E = 100.0f * 1.4426950408889634f;  // T * log2(e)
        float A0[NB], A1[NB], A2[NB], V[NB];
#pragma unroll
        for (int b = 0; b < NB; ++b) {
            A0[b] = a0[b] * TL2E;
            A1[b] = a1[b] * TL2E;
            A2[b] = a2[b] * TL2E;
            V[b]  = vals[b];
        }
        const int n4 = (2048 * 2048) / 4;
        for (; i < n4; i += stride) {
            float4 wv = ((const float4*)w)[i];
            float win[4] = {wv.x, wv.y, wv.z, wv.w};
            u16x4 wr, hr;
#pragma unroll
            for (int c = 0; c < 4; ++c) {
                float xx = win[c];
                float x2 = xx * xx;
                float l[NB];
                float mx = -1e30f;
#pragma unroll
                for (int b = 0; b < NB; ++b) {
                    l[b] = fmaf(A1[b], xx, fmaf(A2[b], x2, A0[b]));   // logits * log2(e)
                    mx = fmaxf(mx, l[b]);
                }
                float s = 0.0f, acc = 0.0f;
#pragma unroll
                for (int b = 0; b < NB; ++b) {
                    float e = __builtin_amdgcn_exp2f(l[b] - mx);      // single v_exp_f32
                    s += e;
                    acc = fmaf(e, V[b], acc);
                }
                wr[c] = f2bf_rtne(xx);
                hr[c] = f2bf_rtne(__fdividef(acc, s));
            }
            *((u16x4*)wbf + i)  = wr;
            *((u16x4*)hwbf + i) = hr;
        }
    }
}

// ---------------- 256x256-tile 8-phase bf16 GEMM: single-barrier phases (LOCKED, r9/r12) ----------------
// Reproduced 64.6-66.4 us across r9/r11/r12/r13. ONE s_barrier between phases; end-barrier only
// after the vmcnt gates at P4/P8. Gate cover 4-6 phases (audited). Conflicts 0; MfmaUtil ~43%.
// 1 block/CU forced: LDS 128KB; acc 128 AGPR + 128 VGPR = 256 regs/wave x 8 waves = full pool.
__global__ __launch_bounds__(512, 2) void gemm256(
    const unsigned short* __restrict__ Ax, const unsigned short* __restrict__ Ah,
    const unsigned short* __restrict__ Bw, const unsigned short* __restrict__ Bh,
    const float* __restrict__ bias,
    float* __restrict__ Cx, float* __restrict__ Chh) {
    const int K = 2048, N = 2048;

    __shared__ unsigned short lds[65536];  // A: [2][16384], B at +32768: [2][16384]

    const unsigned short* A  = blockIdx.z ? Ah : Ax;
    const unsigned short* Bm = blockIdx.z ? Bh : Bw;
    float* C = blockIdx.z ? Chh : Cx;

    const int tid  = threadIdx.x;
    const int lane = tid & 63;
    const int wid  = tid >> 6;
    const int wr = wid >> 2;          // 0..1 : wave row (128 rows)
    const int wc = wid & 3;           // 0..3 : wave col (64 cols)
    const int fr = lane & 15;
    const int fq = lane >> 4;         // 0..3
    const int brow = blockIdx.x;
    const int bcol = blockIdx.y;

    // staging source (pre-swizzled granule): thread t covers row (t>>3), physical granule (t&7)
    const int srow = tid >> 3;                              // 0..63
    const int sg8  = ((tid & 7) ^ (srow & 7)) * 8;          // logical k-offset (elements)
    const unsigned short* gA = A  + (size_t)(brow * 256 + srow) * K + sg8;
    const unsigned short* gB = Bm + (size_t)(bcol * 256 + srow) * K + sg8;
    const int wbase = wid * 512;                            // wave-uniform LDS base (ushorts)

    // ds_read swizzled granule offsets (round-2 pattern, measured 0-conflict)
    const int g0 = (fq ^ (fr & 7)) * 8;   // kk=0
    const int g1 = g0 ^ 32;               // kk=1

#define STAGE_A(buf, h, j) {                                                    \
    const unsigned short* _g = gA + (size_t)((h) * 128) * K + (j) * 64;         \
    gl2lds16(_g,                  lds + (buf) * 16384 + (h) * 8192 + wbase);    \
    gl2lds16(_g + (size_t)64 * K, lds + (buf) * 16384 + (h) * 8192 + 4096 + wbase); }
#define STAGE_B(buf, h, j) {                                                    \
    const unsigned short* _g = gB + (size_t)((h) * 128) * K + (j) * 64;         \
    gl2lds16(_g,                  lds + 32768 + (buf) * 16384 + (h) * 8192 + wbase); \
    gl2lds16(_g + (size_t)64 * K, lds + 32768 + (buf) * 16384 + (h) * 8192 + 4096 + wbase); }

#define RDA(dst, buf, mblk) {                                                   \
    const unsigned short* _p = lds + (buf) * 16384 + (wr * 128 + (mblk) * 16 + fr) * 64; \
    dst[0] = *(const bf16x8*)(_p + g0);                                         \
    dst[1] = *(const bf16x8*)(_p + g1); }
#define RDB(dst, buf, nblk) {                                                   \
    const unsigned short* _p = lds + 32768 + (buf) * 16384 + (wc * 64 + (nblk) * 16 + fr) * 64; \
    dst[0] = *(const bf16x8*)(_p + g0);                                         \
    dst[1] = *(const bf16x8*)(_p + g1); }
#define RD_BURST(buf) { RDB(bfr[0], buf, 0); RDB(bfr[1], buf, 1);               \
                        RDB(bfr[2], buf, 2); RDB(bfr[3], buf, 3); }

#define MM(mi, n, kk, AF) acc[mi][n] = __builtin_amdgcn_mfma_f32_16x16x32_bf16(AF[kk], bfr[n][kk], acc[mi][n], 0, 0, 0)

// phase: bar -> issue reads -> issue stage DMA -> MFMA (counted lgkm) -> [optional gate+bar]
#define PH(q, A0_, A1_, RDS, STG, TAILP) {                                      \
    __builtin_amdgcn_s_barrier();                                               \
    asm volatile("" ::: "memory");                                              \
    RDS;                                                                        \
    STG;                                                                        \
    __builtin_amdgcn_s_setprio(1);                                              \
    MM(2*(q),0,0,A0_); MM(2*(q),0,1,A0_); MM(2*(q)+1,0,0,A1_); MM(2*(q)+1,0,1,A1_); \
    MM(2*(q),1,0,A0_); MM(2*(q),1,1,A0_); MM(2*(q)+1,1,0,A1_); MM(2*(q)+1,1,1,A1_); \
    MM(2*(q),2,0,A0_); MM(2*(q),2,1,A0_); MM(2*(q)+1,2,0,A1_); MM(2*(q)+1,2,1,A1_); \
    MM(2*(q),3,0,A0_); MM(2*(q),3,1,A0_); MM(2*(q)+1,3,0,A1_); MM(2*(q)+1,3,1,A1_); \
    __builtin_amdgcn_s_setprio(0);                                              \
    TAILP;                                                                      \
    asm volatile("" ::: "memory"); }

#define GATE4 { asm volatile("s_waitcnt vmcnt(4)" ::: "memory");                \
                __builtin_amdgcn_s_barrier(); }
#define GATE0 { asm volatile("s_waitcnt vmcnt(0)" ::: "memory");                \
                __builtin_amdgcn_s_barrier(); }

    // prologue: A(0), B(0) -> buf0; B(1) -> buf1 (12 loads); vmcnt(4) leaves B(1) in flight
    STAGE_A(0, 0, 0); STAGE_A(0, 1, 0);
    STAGE_B(0, 0, 0); STAGE_B(0, 1, 0);
    STAGE_B(1, 0, 1); STAGE_B(1, 1, 1);
    asm volatile("s_waitcnt vmcnt(4)" ::: "memory");

    f32x4 acc[8][4] = {};
    bf16x8 bfr[4][2], aU0[2], aU1[2], aV0[2], aV1[2];

    // steady state: tiles 2t (buf0, P1-P4) and 2t+1 (buf1, P5-P8)
    // reads:  P1: burst(b0)+A01->U+A23->V   P2: A45->U   P3: A67->V   P4: -
    //         P5: burst(b1)+A01->U+A23->V   P6: A45->U   P7: A67->V   P8: -
    // stages: P1/P2: A(2t+1)->b1   P3/P4: B(2t+2)->b0 (P4 tail: gate vmcnt(4)+bar)
    //         P5/P6: A(2t+2)->b0   P7/P8: B(2t+3)->b1 (P8 tail: gate vmcnt(4)+bar)
#pragma unroll 1
    for (int t = 0; t < 15; ++t) {
        const int j1 = 2 * t + 1, j2 = 2 * t + 2, j3 = 2 * t + 3;
        PH(0, aU0, aU1, { RD_BURST(0); RDA(aU0,0,0); RDA(aU1,0,1); RDA(aV0,0,2); RDA(aV1,0,3); },
           STAGE_A(1, 0, j1), );
        PH(1, aV0, aV1, { RDA(aU0,0,4); RDA(aU1,0,5); }, STAGE_A(1, 1, j1), );
        PH(2, aU0, aU1, { RDA(aV0,0,6); RDA(aV1,0,7); }, STAGE_B(0, 0, j2), );
        PH(3, aV0, aV1, , STAGE_B(0, 1, j2), GATE4);
        PH(0, aU0, aU1, { RD_BURST(1); RDA(aU0,1,0); RDA(aU1,1,1); RDA(aV0,1,2); RDA(aV1,1,3); },
           STAGE_A(0, 0, j2), );
        PH(1, aV0, aV1, { RDA(aU0,1,4); RDA(aU1,1,5); }, STAGE_A(0, 1, j2), );
        PH(2, aU0, aU1, { RDA(aV0,1,6); RDA(aV1,1,7); }, STAGE_B(1, 0, j3), );
        PH(3, aV0, aV1, , STAGE_B(1, 1, j3), GATE4);
    }
    // tail: tiles 30 (buf0), 31 (buf1); A(31)->buf1 staged here, B(31) staged at t=14
    PH(0, aU0, aU1, { RD_BURST(0); RDA(aU0,0,0); RDA(aU1,0,1); RDA(aV0,0,2); RDA(aV1,0,3); },
       STAGE_A(1, 0, 31), );
    PH(1, aV0, aV1, { RDA(aU0,0,4); RDA(aU1,0,5); }, STAGE_A(1, 1, 31), );
    PH(2, aU0, aU1, { RDA(aV0,0,6); RDA(aV1,0,7); }, , );
    PH(3, aV0, aV1, , , GATE0);
    PH(0, aU0, aU1, { RD_BURST(1); RDA(aU0,1,0); RDA(aU1,1,1); RDA(aV0,1,2); RDA(aV1,1,3); }, , );
    PH(1, aV0, aV1, { RDA(aU0,1,4); RDA(aU1,1,5); }, , );
    PH(2, aU0, aU1, { RDA(aV0,1,6); RDA(aV1,1,7); }, , );
    PH(3, aV0, aV1, , , );

    // epilogue: C[row][col] = acc + bias; row = m*16 + fq*4 + r, col = n*16 + fr (verified mapping)
#pragma unroll
    for (int n = 0; n < 4; ++n) {
        const int col = bcol * 256 + wc * 64 + n * 16 + fr;
        const float bv = bias[col];
#pragma unroll
        for (int m = 0; m < 8; ++m) {
            const int row0 = brow * 256 + wr * 128 + m * 16 + fq * 4;
#pragma unroll
            for (int r = 0; r < 4; ++r)
                C[(size_t)(row0 + r) * N + col] = acc[m][n][r] + bv;
        }
    }
#undef STAGE_A
#undef STAGE_B
#undef RDA
#undef RDB
#undef RD_BURST
#undef MM
#undef PH
#undef GATE4
#undef GATE0
}

extern "C" void kernel_launch(void* const* d_in, const int* in_sizes, int n_in,
                              void* d_out, int out_size, void* d_ws, size_t ws_size,
                              hipStream_t stream) {
    const float* x    = (const float*)d_in[0];
    const float* xh   = (const float*)d_in[1];
    const float* w    = (const float*)d_in[2];
    const float* bias = (const float*)d_in[3];
    const float* a0   = (const float*)d_in[4];
    const float* a1   = (const float*)d_in[5];
    const float* a2   = (const float*)d_in[6];
    const float* vals = (const float*)d_in[7];

    float* out  = (float*)d_out;
    float* outh = out + (size_t)4096 * 2048;

    char* ws = (char*)d_ws;
    unsigned short* xb  = (unsigned short*)(ws);                              // 16 MB
    unsigned short* xhb = (unsigned short*)(ws + (size_t)16 * 1024 * 1024);   // 16 MB
    unsigned short* wb  = (unsigned short*)(ws + (size_t)32 * 1024 * 1024);   //  8 MB
    unsigned short* hwb = (unsigned short*)(ws + (size_t)40 * 1024 * 1024);   //  8 MB

    prep_all<<<dim3(2048, 3), 256, 0, stream>>>(x, xh, w, a0, a1, a2, vals, xb, xhb, wb, hwb);

    dim3 grid(4096 / 256, 2048 / 256, 2);
    gemm256<<<grid, 512, 0, stream>>>(xb, xhb, wb, hwb, bias, out, outh);
}

// Round 15
// 96.836 us; speedup vs baseline: 1.0565x; 1.0395x over previous
//
#include <hip/hip_runtime.h>
#include <hip/hip_bf16.h>

typedef __attribute__((ext_vector_type(8))) short bf16x8;
typedef __attribute__((ext_vector_type(4))) float f32x4;
typedef __attribute__((ext_vector_type(8))) unsigned short u16x8;
typedef __attribute__((ext_vector_type(4))) unsigned short u16x4;

__device__ __forceinline__ unsigned short f2bf_rtne(float f) {
    unsigned int u = __float_as_uint(f);
    u += 0x7FFFu + ((u >> 16) & 1u);
    return (unsigned short)(u >> 16);
}

__device__ __forceinline__ void gl2lds16(const void* g, void* l) {
    __builtin_amdgcn_global_load_lds((const __attribute__((address_space(1))) void*)g,
                                     (__attribute__((address_space(3))) void*)l, 16, 0, 0);
}

// ---------------- fused prep: job0/1 = f32->bf16 convert (x, x_hash); job2 = hash_weight ----------------
// blockIdx.y = job: interleaved across CUs (measured better than contiguous partitioning, r11).
// __expf + plain divide: measured best across 3 math variants (98.2/98.4 vs 102.3 exp2f libm,
// 100.7 builtin exp2 with folded coefficients) — keep the compiler's __expf lowering.
#define NB 16
__global__ void prep_all(const float* __restrict__ x, const float* __restrict__ xh,
                         const float* __restrict__ w,
                         const float* __restrict__ a0, const float* __restrict__ a1,
                         const float* __restrict__ a2, const float* __restrict__ vals,
                         unsigned short* __restrict__ xb, unsigned short* __restrict__ xhb,
                         unsigned short* __restrict__ wbf, unsigned short* __restrict__ hwbf) {
    const int job = blockIdx.y;
    const int stride = gridDim.x * blockDim.x;
    int i = blockIdx.x * blockDim.x + threadIdx.x;
    if (job < 2) {
        const float* in = job ? xh : x;
        unsigned short* out = job ? xhb : xb;
        const int n8 = (4096 * 2048) / 8;
        for (; i < n8; i += stride) {
            const float4* p = (const float4*)in + (size_t)i * 2;
            float4 v0 = p[0];
            float4 v1 = p[1];
            u16x8 r;
            r[0] = f2bf_rtne(v0.x); r[1] = f2bf_rtne(v0.y); r[2] = f2bf_rtne(v0.z); r[3] = f2bf_rtne(v0.w);
            r[4] = f2bf_rtne(v1.x); r[5] = f2bf_rtne(v1.y); r[6] = f2bf_rtne(v1.z); r[7] = f2bf_rtne(v1.w);
            *((u16x8*)out + i) = r;
        }
    } else {
        float A0[NB], A1[NB], A2[NB], V[NB];
#pragma unroll
        for (int b = 0; b < NB; ++b) {
            A0[b] = a0[b] * 100.0f;
            A1[b] = a1[b] * 100.0f;
            A2[b] = a2[b] * 100.0f;
            V[b]  = vals[b];
        }
        const int n4 = (2048 * 2048) / 4;
        for (; i < n4; i += stride) {
            float4 wv = ((const float4*)w)[i];
            float win[4] = {wv.x, wv.y, wv.z, wv.w};
            u16x4 wr, hr;
#pragma unroll
            for (int c = 0; c < 4; ++c) {
                float xx = win[c];
                float x2 = xx * xx;
                float l[NB];
                float mx = -1e30f;
#pragma unroll
                for (int b = 0; b < NB; ++b) {
                    l[b] = fmaf(A1[b], xx, fmaf(A2[b], x2, A0[b]));
                    mx = fmaxf(mx, l[b]);
                }
                float s = 0.0f, acc = 0.0f;
#pragma unroll
                for (int b = 0; b < NB; ++b) {
                    float e = __expf(l[b] - mx);
                    s += e;
                    acc = fmaf(e, V[b], acc);
                }
                wr[c] = f2bf_rtne(xx);
                hr[c] = f2bf_rtne(acc / s);
            }
            *((u16x4*)wbf + i)  = wr;
            *((u16x4*)hwbf + i) = hr;
        }
    }
}

// ---------------- 256x256-tile 8-phase bf16 GEMM: single-barrier phases (FINAL, r9/r12) ----------------
// Reproduced 64.6-66.4 us across r9/r11/r12/r13/r14. ONE s_barrier between phases; end-barrier
// only after the vmcnt gates at P4/P8. Gate cover 4-6 phases (audited). Conflicts 0; MfmaUtil
// ~43%. 1 block/CU forced: LDS 128KB; acc 128 AGPR + 128 VGPR = 256 regs/wave x 8 waves = pool.
__global__ __launch_bounds__(512, 2) void gemm256(
    const unsigned short* __restrict__ Ax, const unsigned short* __restrict__ Ah,
    const unsigned short* __restrict__ Bw, const unsigned short* __restrict__ Bh,
    const float* __restrict__ bias,
    float* __restrict__ Cx, float* __restrict__ Chh) {
    const int K = 2048, N = 2048;

    __shared__ unsigned short lds[65536];  // A: [2][16384], B at +32768: [2][16384]

    const unsigned short* A  = blockIdx.z ? Ah : Ax;
    const unsigned short* Bm = blockIdx.z ? Bh : Bw;
    float* C = blockIdx.z ? Chh : Cx;

    const int tid  = threadIdx.x;
    const int lane = tid & 63;
    const int wid  = tid >> 6;
    const int wr = wid >> 2;          // 0..1 : wave row (128 rows)
    const int wc = wid & 3;           // 0..3 : wave col (64 cols)
    const int fr = lane & 15;
    const int fq = lane >> 4;         // 0..3
    const int brow = blockIdx.x;
    const int bcol = blockIdx.y;

    // staging source (pre-swizzled granule): thread t covers row (t>>3), physical granule (t&7)
    const int srow = tid >> 3;                              // 0..63
    const int sg8  = ((tid & 7) ^ (srow & 7)) * 8;          // logical k-offset (elements)
    const unsigned short* gA = A  + (size_t)(brow * 256 + srow) * K + sg8;
    const unsigned short* gB = Bm + (size_t)(bcol * 256 + srow) * K + sg8;
    const int wbase = wid * 512;                            // wave-uniform LDS base (ushorts)

    // ds_read swizzled granule offsets (round-2 pattern, measured 0-conflict)
    const int g0 = (fq ^ (fr & 7)) * 8;   // kk=0
    const int g1 = g0 ^ 32;               // kk=1

#define STAGE_A(buf, h, j) {                                                    \
    const unsigned short* _g = gA + (size_t)((h) * 128) * K + (j) * 64;         \
    gl2lds16(_g,                  lds + (buf) * 16384 + (h) * 8192 + wbase);    \
    gl2lds16(_g + (size_t)64 * K, lds + (buf) * 16384 + (h) * 8192 + 4096 + wbase); }
#define STAGE_B(buf, h, j) {                                                    \
    const unsigned short* _g = gB + (size_t)((h) * 128) * K + (j) * 64;         \
    gl2lds16(_g,                  lds + 32768 + (buf) * 16384 + (h) * 8192 + wbase); \
    gl2lds16(_g + (size_t)64 * K, lds + 32768 + (buf) * 16384 + (h) * 8192 + 4096 + wbase); }

#define RDA(dst, buf, mblk) {                                                   \
    const unsigned short* _p = lds + (buf) * 16384 + (wr * 128 + (mblk) * 16 + fr) * 64; \
    dst[0] = *(const bf16x8*)(_p + g0);                                         \
    dst[1] = *(const bf16x8*)(_p + g1); }
#define RDB(dst, buf, nblk) {                                                   \
    const unsigned short* _p = lds + 32768 + (buf) * 16384 + (wc * 64 + (nblk) * 16 + fr) * 64; \
    dst[0] = *(const bf16x8*)(_p + g0);                                         \
    dst[1] = *(const bf16x8*)(_p + g1); }
#define RD_BURST(buf) { RDB(bfr[0], buf, 0); RDB(bfr[1], buf, 1);               \
                        RDB(bfr[2], buf, 2); RDB(bfr[3], buf, 3); }

#define MM(mi, n, kk, AF) acc[mi][n] = __builtin_amdgcn_mfma_f32_16x16x32_bf16(AF[kk], bfr[n][kk], acc[mi][n], 0, 0, 0)

// phase: bar -> issue reads -> issue stage DMA -> MFMA (counted lgkm) -> [optional gate+bar]
#define PH(q, A0_, A1_, RDS, STG, TAILP) {                                      \
    __builtin_amdgcn_s_barrier();                                               \
    asm volatile("" ::: "memory");                                              \
    RDS;                                                                        \
    STG;                                                                        \
    __builtin_amdgcn_s_setprio(1);                                              \
    MM(2*(q),0,0,A0_); MM(2*(q),0,1,A0_); MM(2*(q)+1,0,0,A1_); MM(2*(q)+1,0,1,A1_); \
    MM(2*(q),1,0,A0_); MM(2*(q),1,1,A0_); MM(2*(q)+1,1,0,A1_); MM(2*(q)+1,1,1,A1_); \
    MM(2*(q),2,0,A0_); MM(2*(q),2,1,A0_); MM(2*(q)+1,2,0,A1_); MM(2*(q)+1,2,1,A1_); \
    MM(2*(q),3,0,A0_); MM(2*(q),3,1,A0_); MM(2*(q)+1,3,0,A1_); MM(2*(q)+1,3,1,A1_); \
    __builtin_amdgcn_s_setprio(0);                                              \
    TAILP;                                                                      \
    asm volatile("" ::: "memory"); }

#define GATE4 { asm volatile("s_waitcnt vmcnt(4)" ::: "memory");                \
                __builtin_amdgcn_s_barrier(); }
#define GATE0 { asm volatile("s_waitcnt vmcnt(0)" ::: "memory");                \
                __builtin_amdgcn_s_barrier(); }

    // prologue: A(0), B(0) -> buf0; B(1) -> buf1 (12 loads); vmcnt(4) leaves B(1) in flight
    STAGE_A(0, 0, 0); STAGE_A(0, 1, 0);
    STAGE_B(0, 0, 0); STAGE_B(0, 1, 0);
    STAGE_B(1, 0, 1); STAGE_B(1, 1, 1);
    asm volatile("s_waitcnt vmcnt(4)" ::: "memory");

    f32x4 acc[8][4] = {};
    bf16x8 bfr[4][2], aU0[2], aU1[2], aV0[2], aV1[2];

    // steady state: tiles 2t (buf0, P1-P4) and 2t+1 (buf1, P5-P8)
    // reads:  P1: burst(b0)+A01->U+A23->V   P2: A45->U   P3: A67->V   P4: -
    //         P5: burst(b1)+A01->U+A23->V   P6: A45->U   P7: A67->V   P8: -
    // stages: P1/P2: A(2t+1)->b1   P3/P4: B(2t+2)->b0 (P4 tail: gate vmcnt(4)+bar)
    //         P5/P6: A(2t+2)->b0   P7/P8: B(2t+3)->b1 (P8 tail: gate vmcnt(4)+bar)
#pragma unroll 1
    for (int t = 0; t < 15; ++t) {
        const int j1 = 2 * t + 1, j2 = 2 * t + 2, j3 = 2 * t + 3;
        PH(0, aU0, aU1, { RD_BURST(0); RDA(aU0,0,0); RDA(aU1,0,1); RDA(aV0,0,2); RDA(aV1,0,3); },
           STAGE_A(1, 0, j1), );
        PH(1, aV0, aV1, { RDA(aU0,0,4); RDA(aU1,0,5); }, STAGE_A(1, 1, j1), );
        PH(2, aU0, aU1, { RDA(aV0,0,6); RDA(aV1,0,7); }, STAGE_B(0, 0, j2), );
        PH(3, aV0, aV1, , STAGE_B(0, 1, j2), GATE4);
        PH(0, aU0, aU1, { RD_BURST(1); RDA(aU0,1,0); RDA(aU1,1,1); RDA(aV0,1,2); RDA(aV1,1,3); },
           STAGE_A(0, 0, j2), );
        PH(1, aV0, aV1, { RDA(aU0,1,4); RDA(aU1,1,5); }, STAGE_A(0, 1, j2), );
        PH(2, aU0, aU1, { RDA(aV0,1,6); RDA(aV1,1,7); }, STAGE_B(1, 0, j3), );
        PH(3, aV0, aV1, , STAGE_B(1, 1, j3), GATE4);
    }
    // tail: tiles 30 (buf0), 31 (buf1); A(31)->buf1 staged here, B(31) staged at t=14
    PH(0, aU0, aU1, { RD_BURST(0); RDA(aU0,0,0); RDA(aU1,0,1); RDA(aV0,0,2); RDA(aV1,0,3); },
       STAGE_A(1, 0, 31), );
    PH(1, aV0, aV1, { RDA(aU0,0,4); RDA(aU1,0,5); }, STAGE_A(1, 1, 31), );
    PH(2, aU0, aU1, { RDA(aV0,0,6); RDA(aV1,0,7); }, , );
    PH(3, aV0, aV1, , , GATE0);
    PH(0, aU0, aU1, { RD_BURST(1); RDA(aU0,1,0); RDA(aU1,1,1); RDA(aV0,1,2); RDA(aV1,1,3); }, , );
    PH(1, aV0, aV1, { RDA(aU0,1,4); RDA(aU1,1,5); }, , );
    PH(2, aU0, aU1, { RDA(aV0,1,6); RDA(aV1,1,7); }, , );
    PH(3, aV0, aV1, , , );

    // epilogue: C[row][col] = acc + bias; row = m*16 + fq*4 + r, col = n*16 + fr (verified mapping)
#pragma unroll
    for (int n = 0; n < 4; ++n) {
        const int col = bcol * 256 + wc * 64 + n * 16 + fr;
        const float bv = bias[col];
#pragma unroll
        for (int m = 0; m < 8; ++m) {
            const int row0 = brow * 256 + wr * 128 + m * 16 + fq * 4;
#pragma unroll
            for (int r = 0; r < 4; ++r)
                C[(size_t)(row0 + r) * N + col] = acc[m][n][r] + bv;
        }
    }
#undef STAGE_A
#undef STAGE_B
#undef RDA
#undef RDB
#undef RD_BURST
#undef MM
#undef PH
#undef GATE4
#undef GATE0
}

extern "C" void kernel_launch(void* const* d_in, const int* in_sizes, int n_in,
                              void* d_out, int out_size, void* d_ws, size_t ws_size,
                              hipStream_t stream) {
    const float* x    = (const float*)d_in[0];
    const float* xh   = (const float*)d_in[1];
    const float* w    = (const float*)d_in[2];
    const float* bias = (const float*)d_in[3];
    const float* a0   = (const float*)d_in[4];
    const float* a1   = (const float*)d_in[5];
    const float* a2   = (const float*)d_in[6];
    const float* vals = (const float*)d_in[7];

    float* out  = (float*)d_out;
    float* outh = out + (size_t)4096 * 2048;

    char* ws = (char*)d_ws;
    unsigned short* xb  = (unsigned short*)(ws);                              // 16 MB
    unsigned short* xhb = (unsigned short*)(ws + (size_t)16 * 1024 * 1024);   // 16 MB
    unsigned short* wb  = (unsigned short*)(ws + (size_t)32 * 1024 * 1024);   //  8 MB
    unsigned short* hwb = (unsigned short*)(ws + (size_t)40 * 1024 * 1024);   //  8 MB

    prep_all<<<dim3(2048, 3), 256, 0, stream>>>(x, xh, w, a0, a1, a2, vals, xb, xhb, wb, hwb);

    dim3 grid(4096 / 256, 2048 / 256, 2);
    gemm256<<<grid, 512, 0, stream>>>(xb, xhb, wb, hwb, bias, out, outh);
}